// Round 13
// baseline (629.567 us; speedup 1.0000x reference)
//
#include <hip/hip_runtime.h>

#define NV 100000
#define NE 50000
#define NNZ_C 800000
#define CAP_E 64        // slots per edge   (multiple of 16)
#define CAP_V 48        // slots per vertex (multiple of 8)
#define NB_E 391        // ceil(NE/128)
#define NB_V 782        // ceil(NV/128)
#define CAPB_E 2560
#define CAPB_V 1408
#define OVF_CAP 810000
#define T_ITEMS 4096
#define N_TILES ((NNZ_C + T_ITEMS - 1) / T_ITEMS)   // 196
// activations stored as 8 slice-planes of 16 features: plane[s][row][16]
#define ET (NB_E)       // edge tiles of 128
#define VT (NB_V)       // vertex tiles of 128

typedef unsigned int uint32;
typedef unsigned short u16;
typedef u16 u16x8 __attribute__((ext_vector_type(8)));
typedef short short8 __attribute__((ext_vector_type(8)));
typedef float floatx16 __attribute__((ext_vector_type(16)));

__device__ __forceinline__ float bf2f(u16 h) {
  return __uint_as_float(((uint32)h) << 16);
}
__device__ __forceinline__ u16 f2bf(float f) {
  uint32 u = __float_as_uint(f);
  u += 0x7FFF + ((u >> 16) & 1);   // RNE
  return (u16)(u >> 16);
}

// ---------------- zero cursors + dummy rows (slice-major) ----------------

__global__ void zero_misc(int* __restrict__ cur, int n,
                          u16* __restrict__ Xcs, u16* __restrict__ Xes) {
  int i = blockIdx.x * blockDim.x + threadIdx.x;
  if (i < n) cur[i] = 0;
  if (i < 128) {
    int s = i >> 4, j = i & 15;
    Xcs[((size_t)s * (NV + 1) + NV) * 16 + j] = 0;
    Xes[((size_t)s * (NE + 1) + NE) * 16 + j] = 0;
  }
}

// ---------------- LDS-binned scatter (unchanged from R10) ----------------

__global__ __launch_bounds__(256) void scatter_binned(const int* __restrict__ vertex,
                                                      const int* __restrict__ edges,
                                                      int* __restrict__ curE,
                                                      int* __restrict__ curV,
                                                      int* __restrict__ ovfCnt,
                                                      uint32* __restrict__ pairE,
                                                      uint32* __restrict__ pairV,
                                                      uint2* __restrict__ ovfE,
                                                      uint2* __restrict__ ovfV) {
  __shared__ int histE[NB_E], baseE[NB_E];
  __shared__ int histV[NB_V], baseV[NB_V];
  int t = threadIdx.x;
  for (int tile = blockIdx.x; tile < N_TILES; tile += gridDim.x) {
    for (int b = t; b < NB_E; b += 256) histE[b] = 0;
    for (int b = t; b < NB_V; b += 256) histV[b] = 0;
    __syncthreads();
    int base = tile * T_ITEMS;
    int ev[16], vv[16], rE[16], rV[16];
    #pragma unroll
    for (int i = 0; i < 16; i++) {
      int k = base + t + i * 256;
      if (k < NNZ_C) {
        ev[i] = edges[k];
        vv[i] = vertex[k];
        rE[i] = atomicAdd(&histE[ev[i] >> 7], 1);
        rV[i] = atomicAdd(&histV[vv[i] >> 7], 1);
      }
    }
    __syncthreads();
    for (int b = t; b < NB_E; b += 256) {
      int h = histE[b];
      baseE[b] = h ? atomicAdd(&curE[b], h) : 0;
    }
    for (int b = t; b < NB_V; b += 256) {
      int h = histV[b];
      baseV[b] = h ? atomicAdd(&curV[b], h) : 0;
    }
    __syncthreads();
    #pragma unroll
    for (int i = 0; i < 16; i++) {
      int k = base + t + i * 256;
      if (k < NNZ_C) {
        uint32 e = (uint32)ev[i], v = (uint32)vv[i];
        uint32 pkE = ((e & 127u) << 25) | v;
        uint32 pkV = ((v & 127u) << 25) | e;
        int pE = baseE[e >> 7] + rE[i];
        if (pE < CAPB_E) pairE[(size_t)(e >> 7) * CAPB_E + pE] = pkE;
        else { int op = atomicAdd(&ovfCnt[0], 1); if (op < OVF_CAP) ovfE[op] = make_uint2(e >> 7, pkE); }
        int pV = baseV[v >> 7] + rV[i];
        if (pV < CAPB_V) pairV[(size_t)(v >> 7) * CAPB_V + pV] = pkV;
        else { int op = atomicAdd(&ovfCnt[1], 1); if (op < OVF_CAP) ovfV[op] = make_uint2(v >> 7, pkV); }
      }
    }
    __syncthreads();
  }
}

__global__ __launch_bounds__(256) void expand(const uint32* __restrict__ pairs,
                                              const int* __restrict__ cur, int capb,
                                              const uint2* __restrict__ ovf,
                                              const int* __restrict__ ovfCnt,
                                              int* __restrict__ items, int cap,
                                              int* __restrict__ cnt, int nKeys,
                                              int P, int dummy) {
  __shared__ int lcnt[128];
  int b = blockIdx.x, t = threadIdx.x;
  if (t < 128) lcnt[t] = 0;
  __syncthreads();
  int n = min(cur[b], capb);
  const uint32* p = pairs + (size_t)b * capb;
  for (int i = t; i < n; i += 256) {
    uint32 w = p[i];
    int loc = w >> 25;
    int val = (int)(w & 0x1FFFFFFu);
    int r = atomicAdd(&lcnt[loc], 1);
    if (r < cap) items[(size_t)((b << 7) + loc) * cap + r] = val;
  }
  int novf = min(*ovfCnt, OVF_CAP);
  for (int i = t; i < novf; i += 256) {
    uint2 w = ovf[i];
    if ((int)w.x == b) {
      int loc = w.y >> 25;
      int val = (int)(w.y & 0x1FFFFFFu);
      int r = atomicAdd(&lcnt[loc], 1);
      if (r < cap) items[(size_t)((b << 7) + loc) * cap + r] = val;
    }
  }
  __syncthreads();
  if (t < 128) {
    int key = (b << 7) + t;
    if (key < nKeys) {
      int c = lcnt[t];
      cnt[key] = c;
      int cc = min(c, cap);
      int padded = min((cc + P - 1) & ~(P - 1), cap);
      for (int r = cc; r < padded; r++)
        items[(size_t)key * cap + r] = dummy;
    }
  }
}

// ---------------- weight prep ----------------

__global__ void prep_weights(const float* __restrict__ W0, const float* __restrict__ Ws,
                             u16* __restrict__ WT) {
  int idx = blockIdx.x * blockDim.x + threadIdx.x;
  if (idx >= 5 * 16384) return;
  const float betas[4] = {0.4054651081f, 0.2231435513f, 0.1541506798f, 0.1177830357f};
  int sec = idx >> 14;
  int rc = idx & 16383;
  int n = rc >> 7, k = rc & 127;
  float v;
  if (sec == 0) {
    v = W0[k * 128 + n];
  } else {
    int i = sec - 1;
    float b = betas[i];
    v = b * Ws[i * 16384 + k * 128 + n];
    if (k == n) v += 1.0f - b;
  }
  WT[idx] = f2bf(v);
}

// ---------------- sliced edge aggregation ----------------
// block = (edge-tile of 128, slice); slice = blockIdx%8 -> rides the XCD
// round-robin so each XCD's gathers stay in a 3.2 MB L2-resident plane.

__global__ __launch_bounds__(256) void edge_agg_s(const u16* __restrict__ Xcs,
                                                  const int* __restrict__ cntE,
                                                  const int* __restrict__ itemsE,
                                                  u16* __restrict__ Xes) {
  int s = blockIdx.x & 7;
  int tile = blockIdx.x >> 3;
  int t = threadIdx.x;
  int p = t >> 1, half = t & 1;
  int e = tile * 128 + p;
  if (e >= NE) return;
  int cnt = cntE[e];
  int n16 = (min(cnt, CAP_E) + 15) & ~15;
  const int* it = itemsE + (size_t)e * CAP_E;
  const u16* src = Xcs + (size_t)s * (NV + 1) * 16 + half * 8;
  float acc[8] = {0.f, 0.f, 0.f, 0.f, 0.f, 0.f, 0.f, 0.f};
  for (int j = 0; j < n16; j += 16) {
    int4 i0 = *(const int4*)(it + j);
    int4 i1 = *(const int4*)(it + j + 4);
    int4 i2 = *(const int4*)(it + j + 8);
    int4 i3 = *(const int4*)(it + j + 12);
    u16x8 r0 = *(const u16x8*)(src + (size_t)i0.x * 16);
    u16x8 r1 = *(const u16x8*)(src + (size_t)i0.y * 16);
    u16x8 r2 = *(const u16x8*)(src + (size_t)i0.z * 16);
    u16x8 r3 = *(const u16x8*)(src + (size_t)i0.w * 16);
    u16x8 r4 = *(const u16x8*)(src + (size_t)i1.x * 16);
    u16x8 r5 = *(const u16x8*)(src + (size_t)i1.y * 16);
    u16x8 r6 = *(const u16x8*)(src + (size_t)i1.z * 16);
    u16x8 r7 = *(const u16x8*)(src + (size_t)i1.w * 16);
    u16x8 r8 = *(const u16x8*)(src + (size_t)i2.x * 16);
    u16x8 r9 = *(const u16x8*)(src + (size_t)i2.y * 16);
    u16x8 rA = *(const u16x8*)(src + (size_t)i2.z * 16);
    u16x8 rB = *(const u16x8*)(src + (size_t)i2.w * 16);
    u16x8 rC = *(const u16x8*)(src + (size_t)i3.x * 16);
    u16x8 rD = *(const u16x8*)(src + (size_t)i3.y * 16);
    u16x8 rE = *(const u16x8*)(src + (size_t)i3.z * 16);
    u16x8 rF = *(const u16x8*)(src + (size_t)i3.w * 16);
    #pragma unroll
    for (int q = 0; q < 8; q++) {
      float s0 = (bf2f(r0[q]) + bf2f(r1[q])) + (bf2f(r2[q]) + bf2f(r3[q]));
      float s1 = (bf2f(r4[q]) + bf2f(r5[q])) + (bf2f(r6[q]) + bf2f(r7[q]));
      float s2 = (bf2f(r8[q]) + bf2f(r9[q])) + (bf2f(rA[q]) + bf2f(rB[q]));
      float s3 = (bf2f(rC[q]) + bf2f(rD[q])) + (bf2f(rE[q]) + bf2f(rF[q]));
      acc[q] += (s0 + s1) + (s2 + s3);
    }
  }
  float inv = 1.f / fmaxf((float)cnt, 1.f);
  u16x8 o;
  #pragma unroll
  for (int q = 0; q < 8; q++) o[q] = f2bf(acc[q] * inv);
  *(u16x8*)(Xes + ((size_t)s * (NE + 1) + e) * 16 + half * 8) = o;
}

// ---------------- sliced vertex gather: per-slice mean + partial sumsq ----------------

__global__ __launch_bounds__(256) void vertex_gather_s(const u16* __restrict__ Xes,
                                                       const int* __restrict__ cntV,
                                                       const int* __restrict__ itemsV,
                                                       u16* __restrict__ Xvs,
                                                       float* __restrict__ nb) {
  int s = blockIdx.x & 7;
  int tile = blockIdx.x >> 3;
  int t = threadIdx.x;
  int p = t >> 1, half = t & 1;
  int v = tile * 128 + p;
  if (v >= NV) return;
  int cnt = cntV[v];
  int n8 = (min(cnt, CAP_V) + 7) & ~7;
  const int* it = itemsV + (size_t)v * CAP_V;
  const u16* src = Xes + (size_t)s * (NE + 1) * 16 + half * 8;
  float acc[8] = {0.f, 0.f, 0.f, 0.f, 0.f, 0.f, 0.f, 0.f};
  for (int j = 0; j < n8; j += 8) {
    int4 e0 = *(const int4*)(it + j);
    int4 e1 = *(const int4*)(it + j + 4);
    u16x8 r0 = *(const u16x8*)(src + (size_t)e0.x * 16);
    u16x8 r1 = *(const u16x8*)(src + (size_t)e0.y * 16);
    u16x8 r2 = *(const u16x8*)(src + (size_t)e0.z * 16);
    u16x8 r3 = *(const u16x8*)(src + (size_t)e0.w * 16);
    u16x8 r4 = *(const u16x8*)(src + (size_t)e1.x * 16);
    u16x8 r5 = *(const u16x8*)(src + (size_t)e1.y * 16);
    u16x8 r6 = *(const u16x8*)(src + (size_t)e1.z * 16);
    u16x8 r7 = *(const u16x8*)(src + (size_t)e1.w * 16);
    #pragma unroll
    for (int q = 0; q < 8; q++)
      acc[q] += ((bf2f(r0[q]) + bf2f(r1[q])) + (bf2f(r2[q]) + bf2f(r3[q]))) +
                ((bf2f(r4[q]) + bf2f(r5[q])) + (bf2f(r6[q]) + bf2f(r7[q])));
  }
  float inv = 1.f / fmaxf((float)cnt, 1.f);
  u16x8 o;
  float sq = 0.f;
  #pragma unroll
  for (int q = 0; q < 8; q++) {
    o[q] = f2bf(acc[q] * inv);
    float m = bf2f(o[q]);          // sumsq of the rounded values (matches stored)
    sq += m * m;
  }
  sq += __shfl_xor(sq, 1, 64);     // pair-sum -> slice sumsq
  if (half == 0) nb[(size_t)s * NV + v] = sq;
  *(u16x8*)(Xvs + ((size_t)s * NV + v) * 16 + half * 8) = o;
}

// ---------------- norm + blend + MFMA GEMM (sequential reads) ----------------
// A frag: row = lane&31, k = (lane>>5)*8 + j.  C/D: col = lane&31,
// row = (reg&3) + 8*(reg>>2) + 4*(lane>>5)  [m74/m101-verified]

__global__ __launch_bounds__(256, 5) void gemm_norm(const u16* __restrict__ Xvs,
                                                    const float* __restrict__ nb,
                                                    const u16* __restrict__ x0s,
                                                    const u16* __restrict__ WT,
                                                    u16* __restrict__ Xcs, int nrows) {
  __shared__ u16 As[64 * 136];
  int t = threadIdx.x;
  int row0 = blockIdx.x * 64;
  int g = t >> 4, lane = t & 15;
  int sl = lane >> 1, half = lane & 1;
  #pragma unroll
  for (int pass = 0; pass < 4; pass++) {
    int r = pass * 16 + g;
    int v = row0 + r;
    u16x8 mv = {0, 0, 0, 0, 0, 0, 0, 0};
    u16x8 x0v = {0, 0, 0, 0, 0, 0, 0, 0};
    float nbv = 0.f;
    if (v < nrows) {
      size_t off = ((size_t)sl * NV + v) * 16 + half * 8;
      mv = *(const u16x8*)(Xvs + off);
      x0v = *(const u16x8*)(x0s + off);
      nbv = (lane < 8) ? nb[(size_t)lane * NV + v] : 0.f;
    }
    float sq = nbv;
    sq += __shfl_xor(sq, 1, 64);
    sq += __shfl_xor(sq, 2, 64);
    sq += __shfl_xor(sq, 4, 64);
    sq += __shfl_xor(sq, 8, 64);
    float scale = (sq > 0.f) ? rsqrtf(sq) : 0.f;
    u16x8 o;
    #pragma unroll
    for (int q = 0; q < 8; q++)
      o[q] = f2bf(0.9f * bf2f(mv[q]) * scale + 0.1f * bf2f(x0v[q]));
    *(u16x8*)&As[r * 136 + lane * 8] = o;
  }
  __syncthreads();

  int w = t >> 6, lane64 = t & 63;
  int l31 = lane64 & 31, kh = lane64 >> 5;
  int wr = w >> 1, wc = w & 1;
  floatx16 acc[2];
  #pragma unroll
  for (int ct = 0; ct < 2; ct++)
    #pragma unroll
    for (int q = 0; q < 16; q++) acc[ct][q] = 0.f;

  const u16* wtb0 = WT + (size_t)(wc * 64 + l31) * 128;
  const u16* wtb1 = WT + (size_t)(wc * 64 + 32 + l31) * 128;
  #pragma unroll
  for (int ks = 0; ks < 8; ks++) {
    int koff = ks * 16 + kh * 8;
    short8 b0 = *(const short8*)(wtb0 + koff);
    short8 b1 = *(const short8*)(wtb1 + koff);
    short8 a0 = *(const short8*)&As[(wr * 32 + l31) * 136 + koff];
    acc[0] = __builtin_amdgcn_mfma_f32_32x32x16_bf16(a0, b0, acc[0], 0, 0, 0);
    acc[1] = __builtin_amdgcn_mfma_f32_32x32x16_bf16(a0, b1, acc[1], 0, 0, 0);
  }
  __syncthreads();

  #pragma unroll
  for (int ct = 0; ct < 2; ct++) {
    int col = wc * 64 + ct * 32 + l31;
    #pragma unroll
    for (int reg = 0; reg < 16; reg++) {
      int row = wr * 32 + (reg & 3) + 8 * (reg >> 2) + 4 * kh;
      As[row * 136 + col] = f2bf(fmaxf(acc[ct][reg], 0.f));
    }
  }
  __syncthreads();
  #pragma unroll
  for (int i = 0; i < 4; i++) {
    int idx = t + 256 * i;
    int r = idx >> 4, c8 = idx & 15;
    if (row0 + r < nrows)
      *(u16x8*)(Xcs + ((size_t)(c8 >> 1) * (NV + 1) + row0 + r) * 16 + (c8 & 1) * 8) =
          *(const u16x8*)&As[r * 136 + c8 * 8];
  }
}

// first GEMM: fp32 A in, +bias, relu; writes x_cur & x0 slice-major
__global__ __launch_bounds__(256, 4) void gemm_first(const float* __restrict__ A,
                                                     const u16* __restrict__ WT,
                                                     const float* __restrict__ bias,
                                                     u16* __restrict__ Xcs,
                                                     u16* __restrict__ x0s, int nrows) {
  __shared__ u16 As[128 * 136];
  int t = threadIdx.x;
  int row0 = blockIdx.x * 128;
  #pragma unroll
  for (int i = 0; i < 8; i++) {
    int idx = t + 256 * i;
    int r = idx >> 4, c8 = idx & 15;
    u16x8 v = {0, 0, 0, 0, 0, 0, 0, 0};
    if (row0 + r < nrows) {
      const float* p = A + (size_t)(row0 + r) * 128 + c8 * 8;
      float4 a = *(const float4*)p;
      float4 b = *(const float4*)(p + 4);
      v[0] = f2bf(a.x); v[1] = f2bf(a.y); v[2] = f2bf(a.z); v[3] = f2bf(a.w);
      v[4] = f2bf(b.x); v[5] = f2bf(b.y); v[6] = f2bf(b.z); v[7] = f2bf(b.w);
    }
    *(u16x8*)&As[r * 136 + c8 * 8] = v;
  }
  __syncthreads();

  int w = t >> 6, lane = t & 63;
  int l31 = lane & 31, kh = lane >> 5;
  int wr = w >> 1, wc = w & 1;
  floatx16 acc[2][2];
  #pragma unroll
  for (int rt = 0; rt < 2; rt++)
    #pragma unroll
    for (int ct = 0; ct < 2; ct++)
      #pragma unroll
      for (int q = 0; q < 16; q++) acc[rt][ct][q] = 0.f;

  const u16* wtb0 = WT + (size_t)(wc * 64 + l31) * 128;
  const u16* wtb1 = WT + (size_t)(wc * 64 + 32 + l31) * 128;
  #pragma unroll
  for (int ks = 0; ks < 8; ks++) {
    int koff = ks * 16 + kh * 8;
    short8 b0 = *(const short8*)(wtb0 + koff);
    short8 b1 = *(const short8*)(wtb1 + koff);
    short8 a0 = *(const short8*)&As[(wr * 64 + l31) * 136 + koff];
    short8 a1 = *(const short8*)&As[(wr * 64 + 32 + l31) * 136 + koff];
    acc[0][0] = __builtin_amdgcn_mfma_f32_32x32x16_bf16(a0, b0, acc[0][0], 0, 0, 0);
    acc[0][1] = __builtin_amdgcn_mfma_f32_32x32x16_bf16(a0, b1, acc[0][1], 0, 0, 0);
    acc[1][0] = __builtin_amdgcn_mfma_f32_32x32x16_bf16(a1, b0, acc[1][0], 0, 0, 0);
    acc[1][1] = __builtin_amdgcn_mfma_f32_32x32x16_bf16(a1, b1, acc[1][1], 0, 0, 0);
  }
  __syncthreads();

  #pragma unroll
  for (int rt = 0; rt < 2; rt++)
    #pragma unroll
    for (int ct = 0; ct < 2; ct++) {
      int col = wc * 64 + ct * 32 + l31;
      float bv = bias[col];
      #pragma unroll
      for (int reg = 0; reg < 16; reg++) {
        int row = wr * 64 + rt * 32 + (reg & 3) + 8 * (reg >> 2) + 4 * kh;
        As[row * 136 + col] = f2bf(fmaxf(acc[rt][ct][reg] + bv, 0.f));
      }
    }
  __syncthreads();
  #pragma unroll
  for (int i = 0; i < 8; i++) {
    int idx = t + 256 * i;
    int r = idx >> 4, c8 = idx & 15;
    if (row0 + r < nrows) {
      u16x8 v = *(const u16x8*)&As[r * 136 + c8 * 8];
      int sl = c8 >> 1, hf = c8 & 1;
      *(u16x8*)(Xcs + ((size_t)sl * (NV + 1) + row0 + r) * 16 + hf * 8) = v;
      *(u16x8*)(x0s + ((size_t)sl * NV + row0 + r) * 16 + hf * 8) = v;
    }
  }
}

// ---------------- output GEMM: out[nrows,40] = Xc @ Wout + bout ----------------

__global__ __launch_bounds__(256) void gemm_out(const u16* __restrict__ Xcs,
                                                const float* __restrict__ W,
                                                const float* __restrict__ bias,
                                                float* __restrict__ Y, int nrows) {
  __shared__ float xs[128][36];
  __shared__ float ws[32][44];
  int t = threadIdx.x;
  int tr = t >> 3;
  int tc = t & 7;
  int row0 = blockIdx.x * 128;
  float acc[4][5];
  #pragma unroll
  for (int i = 0; i < 4; i++)
    #pragma unroll
    for (int j = 0; j < 5; j++) acc[i][j] = 0.f;

  for (int k0 = 0; k0 < 128; k0 += 32) {
    #pragma unroll
    for (int i = 0; i < 2; i++) {
      int idx = t + 256 * i;
      int r = idx >> 2, c8 = idx & 3;
      int gr = row0 + r;
      u16x8 v = {0, 0, 0, 0, 0, 0, 0, 0};
      if (gr < nrows) {
        int f = k0 + c8 * 8;
        v = *(const u16x8*)(Xcs + ((size_t)(f >> 4) * (NV + 1) + gr) * 16 + (f & 15));
      }
      #pragma unroll
      for (int q = 0; q < 8; q++) xs[r][c8 * 8 + q] = bf2f(v[q]);
    }
    #pragma unroll
    for (int i = 0; i < 5; i++) {
      int idx = t + 256 * i;
      int r = idx / 40, c = idx % 40;
      ws[r][c] = W[(k0 + r) * 40 + c];
    }
    __syncthreads();
    #pragma unroll
    for (int kk4 = 0; kk4 < 8; kk4++) {
      float4 xv[4];
      #pragma unroll
      for (int i = 0; i < 4; i++) xv[i] = *(const float4*)&xs[tr + 32 * i][kk4 * 4];
      #pragma unroll
      for (int q = 0; q < 4; q++) {
        int kk = kk4 * 4 + q;
        float wv[5];
        #pragma unroll
        for (int j = 0; j < 5; j++) wv[j] = ws[kk][tc * 5 + j];
        #pragma unroll
        for (int i = 0; i < 4; i++) {
          float xq = ((const float*)&xv[i])[q];
          #pragma unroll
          for (int j = 0; j < 5; j++) acc[i][j] += xq * wv[j];
        }
      }
    }
    __syncthreads();
  }
  #pragma unroll
  for (int i = 0; i < 4; i++) {
    int gr = row0 + tr + 32 * i;
    if (gr >= nrows) continue;
    #pragma unroll
    for (int j = 0; j < 5; j++) {
      int c = tc * 5 + j;
      Y[(long)gr * 40 + c] = acc[i][j] + bias[c];
    }
  }
}

// ---------------- launch ----------------

extern "C" void kernel_launch(void* const* d_in, const int* in_sizes, int n_in,
                              void* d_out, int out_size, void* d_ws, size_t ws_size,
                              hipStream_t stream) {
  const float* x    = (const float*)d_in[0];
  const float* W0   = (const float*)d_in[1];
  const float* b0   = (const float*)d_in[2];
  const float* Ws   = (const float*)d_in[3];
  const float* Wout = (const float*)d_in[4];
  const float* bout = (const float*)d_in[5];
  const int* vertex = (const int*)d_in[6];
  const int* edges  = (const int*)d_in[7];
  float* out = (float*)d_out;

  char* base = (char*)d_ws;
  size_t o = 0;
  auto alloc = [&](size_t bytes) -> char* {
    char* r = base + o;
    o += (bytes + 255) & ~(size_t)255;
    return r;
  };
  u16* Xcs  = (u16*)alloc((size_t)8 * (NV + 1) * 16 * 2);  // x_cur, slice-major (+dummy)
  u16* x0s  = (u16*)alloc((size_t)8 * NV * 16 * 2);
  u16* Xes  = (u16*)alloc((size_t)8 * (NE + 1) * 16 * 2);  // Xe, slice-major (+dummy)
  u16* Xvs  = (u16*)alloc((size_t)8 * NV * 16 * 2);        // vertex means, slice-major
  float* nbuf = (float*)alloc((size_t)8 * NV * 4);         // per-slice sumsq
  u16* WT   = (u16*)alloc((size_t)5 * 16384 * 2);
  int* cntE   = (int*)alloc((size_t)NE * 4);
  int* cntV   = (int*)alloc((size_t)NV * 4);
  int* itemsE = (int*)alloc((size_t)NE * CAP_E * 4);
  int* itemsV = (int*)alloc((size_t)NV * CAP_V * 4);
  uint32* pairE = (uint32*)alloc((size_t)NB_E * CAPB_E * 4);
  uint32* pairV = (uint32*)alloc((size_t)NB_V * CAPB_V * 4);
  uint2* ovfE  = (uint2*)alloc((size_t)OVF_CAP * 8);
  uint2* ovfV  = (uint2*)alloc((size_t)OVF_CAP * 8);
  int* curAll = (int*)alloc((size_t)(NB_E + NB_V + 2) * 4);
  int* curE = curAll;
  int* curV = curAll + NB_E;
  int* ovfCnt = curAll + NB_E + NB_V;

  int nzero = NB_E + NB_V + 2;
  zero_misc<<<(nzero + 255) / 256, 256, 0, stream>>>(curAll, nzero, Xcs, Xes);
  scatter_binned<<<N_TILES, 256, 0, stream>>>(vertex, edges, curE, curV, ovfCnt,
                                              pairE, pairV, ovfE, ovfV);
  expand<<<NB_E, 256, 0, stream>>>(pairE, curE, CAPB_E, ovfE, ovfCnt,
                                   itemsE, CAP_E, cntE, NE, 16, NV);
  expand<<<NB_V, 256, 0, stream>>>(pairV, curV, CAPB_V, ovfV, ovfCnt + 1,
                                   itemsV, CAP_V, cntV, NV, 8, NE);
  prep_weights<<<(5 * 16384 + 255) / 256, 256, 0, stream>>>(W0, Ws, WT);

  int gblocks = (NV + 127) / 128;
  int fblocks = (NV + 63) / 64;
  gemm_first<<<gblocks, 256, 0, stream>>>(x, WT, b0, Xcs, x0s, NV);

  for (int i = 0; i < 4; i++) {
    edge_agg_s<<<ET * 8, 256, 0, stream>>>(Xcs, cntE, itemsE, Xes);
    vertex_gather_s<<<VT * 8, 256, 0, stream>>>(Xes, cntV, itemsV, Xvs, nbuf);
    gemm_norm<<<fblocks, 256, 0, stream>>>(Xvs, nbuf, x0s,
                                           WT + (size_t)(1 + i) * 16384, Xcs, NV);
  }
  gemm_out<<<gblocks, 256, 0, stream>>>(Xcs, Wout, bout, out, NV);
}

// Round 14
// 488.321 us; speedup vs baseline: 1.2892x; 1.2892x over previous
//
#include <hip/hip_runtime.h>

#define NV 100000
#define NE 50000
#define NNZ_C 800000
#define CAP_E 64        // slots per edge   (multiple of 16)
#define CAP_V 48        // slots per vertex (multiple of 8)
#define NB_E 391        // ceil(NE/128)
#define NB_V 782        // ceil(NV/128)
#define CAPB_E 2560
#define CAPB_V 1408
#define OVF_CAP 810000
#define T_ITEMS 4096
#define N_TILES ((NNZ_C + T_ITEMS - 1) / T_ITEMS)   // 196

typedef unsigned int uint32;
typedef unsigned short u16;
typedef u16 u16x8 __attribute__((ext_vector_type(8)));
typedef short short8 __attribute__((ext_vector_type(8)));
typedef float floatx16 __attribute__((ext_vector_type(16)));

__device__ __forceinline__ float bf2f(u16 h) {
  return __uint_as_float(((uint32)h) << 16);
}
__device__ __forceinline__ u16 f2bf(float f) {
  uint32 u = __float_as_uint(f);
  u += 0x7FFF + ((u >> 16) & 1);   // RNE
  return (u16)(u >> 16);
}

// ---------------- zero cursors + dummy gather rows ----------------

__global__ void zero_misc(int* __restrict__ cur, int n,
                          u16* __restrict__ dummyX, u16* __restrict__ dummyXe) {
  int i = blockIdx.x * blockDim.x + threadIdx.x;
  if (i < n) cur[i] = 0;
  if (i < 128) { dummyX[i] = 0; dummyXe[i] = 0; }
}

// ---------------- LDS-binned scatter ----------------

__global__ __launch_bounds__(256) void scatter_binned(const int* __restrict__ vertex,
                                                      const int* __restrict__ edges,
                                                      int* __restrict__ curE,
                                                      int* __restrict__ curV,
                                                      int* __restrict__ ovfCnt,
                                                      uint32* __restrict__ pairE,
                                                      uint32* __restrict__ pairV,
                                                      uint2* __restrict__ ovfE,
                                                      uint2* __restrict__ ovfV) {
  __shared__ int histE[NB_E], baseE[NB_E];
  __shared__ int histV[NB_V], baseV[NB_V];
  int t = threadIdx.x;
  for (int tile = blockIdx.x; tile < N_TILES; tile += gridDim.x) {
    for (int b = t; b < NB_E; b += 256) histE[b] = 0;
    for (int b = t; b < NB_V; b += 256) histV[b] = 0;
    __syncthreads();
    int base = tile * T_ITEMS;
    int ev[16], vv[16], rE[16], rV[16];
    #pragma unroll
    for (int i = 0; i < 16; i++) {
      int k = base + t + i * 256;
      if (k < NNZ_C) {
        ev[i] = edges[k];
        vv[i] = vertex[k];
        rE[i] = atomicAdd(&histE[ev[i] >> 7], 1);
        rV[i] = atomicAdd(&histV[vv[i] >> 7], 1);
      }
    }
    __syncthreads();
    for (int b = t; b < NB_E; b += 256) {
      int h = histE[b];
      baseE[b] = h ? atomicAdd(&curE[b], h) : 0;
    }
    for (int b = t; b < NB_V; b += 256) {
      int h = histV[b];
      baseV[b] = h ? atomicAdd(&curV[b], h) : 0;
    }
    __syncthreads();
    #pragma unroll
    for (int i = 0; i < 16; i++) {
      int k = base + t + i * 256;
      if (k < NNZ_C) {
        uint32 e = (uint32)ev[i], v = (uint32)vv[i];
        uint32 pkE = ((e & 127u) << 25) | v;
        uint32 pkV = ((v & 127u) << 25) | e;
        int pE = baseE[e >> 7] + rE[i];
        if (pE < CAPB_E) pairE[(size_t)(e >> 7) * CAPB_E + pE] = pkE;
        else { int op = atomicAdd(&ovfCnt[0], 1); if (op < OVF_CAP) ovfE[op] = make_uint2(e >> 7, pkE); }
        int pV = baseV[v >> 7] + rV[i];
        if (pV < CAPB_V) pairV[(size_t)(v >> 7) * CAPB_V + pV] = pkV;
        else { int op = atomicAdd(&ovfCnt[1], 1); if (op < OVF_CAP) ovfV[op] = make_uint2(v >> 7, pkV); }
      }
    }
    __syncthreads();
  }
}

// rank via LDS atomics; 32-bit items (edge side: values are vertex ids >= 2^16)
__global__ __launch_bounds__(256) void expand(const uint32* __restrict__ pairs,
                                              const int* __restrict__ cur, int capb,
                                              const uint2* __restrict__ ovf,
                                              const int* __restrict__ ovfCnt,
                                              int* __restrict__ items, int cap,
                                              int* __restrict__ cnt, int nKeys,
                                              int P, int dummy) {
  __shared__ int lcnt[128];
  int b = blockIdx.x, t = threadIdx.x;
  if (t < 128) lcnt[t] = 0;
  __syncthreads();
  int n = min(cur[b], capb);
  const uint32* p = pairs + (size_t)b * capb;
  for (int i = t; i < n; i += 256) {
    uint32 w = p[i];
    int loc = w >> 25;
    int val = (int)(w & 0x1FFFFFFu);
    int r = atomicAdd(&lcnt[loc], 1);
    if (r < cap) items[(size_t)((b << 7) + loc) * cap + r] = val;
  }
  int novf = min(*ovfCnt, OVF_CAP);
  for (int i = t; i < novf; i += 256) {
    uint2 w = ovf[i];
    if ((int)w.x == b) {
      int loc = w.y >> 25;
      int val = (int)(w.y & 0x1FFFFFFu);
      int r = atomicAdd(&lcnt[loc], 1);
      if (r < cap) items[(size_t)((b << 7) + loc) * cap + r] = val;
    }
  }
  __syncthreads();
  if (t < 128) {
    int key = (b << 7) + t;
    if (key < nKeys) {
      int c = lcnt[t];
      cnt[key] = c;
      int cc = min(c, cap);
      int padded = min((cc + P - 1) & ~(P - 1), cap);
      for (int r = cc; r < padded; r++)
        items[(size_t)key * cap + r] = dummy;
    }
  }
}

// u16 variant (vertex side: values are edge ids < 65536; dummy = NE fits)
__global__ __launch_bounds__(256) void expand16(const uint32* __restrict__ pairs,
                                                const int* __restrict__ cur, int capb,
                                                const uint2* __restrict__ ovf,
                                                const int* __restrict__ ovfCnt,
                                                u16* __restrict__ items, int cap,
                                                int* __restrict__ cnt, int nKeys,
                                                int P, int dummy) {
  __shared__ int lcnt[128];
  int b = blockIdx.x, t = threadIdx.x;
  if (t < 128) lcnt[t] = 0;
  __syncthreads();
  int n = min(cur[b], capb);
  const uint32* p = pairs + (size_t)b * capb;
  for (int i = t; i < n; i += 256) {
    uint32 w = p[i];
    int loc = w >> 25;
    int val = (int)(w & 0x1FFFFFFu);
    int r = atomicAdd(&lcnt[loc], 1);
    if (r < cap) items[(size_t)((b << 7) + loc) * cap + r] = (u16)val;
  }
  int novf = min(*ovfCnt, OVF_CAP);
  for (int i = t; i < novf; i += 256) {
    uint2 w = ovf[i];
    if ((int)w.x == b) {
      int loc = w.y >> 25;
      int val = (int)(w.y & 0x1FFFFFFu);
      int r = atomicAdd(&lcnt[loc], 1);
      if (r < cap) items[(size_t)((b << 7) + loc) * cap + r] = (u16)val;
    }
  }
  __syncthreads();
  if (t < 128) {
    int key = (b << 7) + t;
    if (key < nKeys) {
      int c = lcnt[t];
      cnt[key] = c;
      int cc = min(c, cap);
      int padded = min((cc + P - 1) & ~(P - 1), cap);
      for (int r = cc; r < padded; r++)
        items[(size_t)key * cap + r] = (u16)dummy;
    }
  }
}

// ---------------- weight prep ----------------
// WT: [0,16384) = W0T[n][k]; then 4x WeffT[i][n][k], Weff=(1-b)I+b*Ws[i]

__global__ void prep_weights(const float* __restrict__ W0, const float* __restrict__ Ws,
                             u16* __restrict__ WT) {
  int idx = blockIdx.x * blockDim.x + threadIdx.x;
  if (idx >= 5 * 16384) return;
  const float betas[4] = {0.4054651081f, 0.2231435513f, 0.1541506798f, 0.1177830357f};
  int sec = idx >> 14;
  int rc = idx & 16383;
  int n = rc >> 7, k = rc & 127;
  float v;
  if (sec == 0) {
    v = W0[k * 128 + n];
  } else {
    int i = sec - 1;
    float b = betas[i];
    v = b * Ws[i * 16384 + k * 128 + n];
    if (k == n) v += 1.0f - b;
  }
  WT[idx] = f2bf(v);
}

// ---------------- edge aggregation (bf16, 16 lanes/row, guard-free) ----------------

__global__ __launch_bounds__(256) void edge_agg(const u16* __restrict__ Xh,
                                                const int* __restrict__ cntE,
                                                const int* __restrict__ itemsE,
                                                u16* __restrict__ Xeh) {
  int g = threadIdx.x >> 4;
  int lane = threadIdx.x & 15;
  int e = blockIdx.x * 16 + g;
  int cnt = cntE[e];
  int n16 = (min(cnt, CAP_E) + 15) & ~15;
  const int* it = itemsE + (size_t)e * CAP_E;
  float acc[8] = {0.f, 0.f, 0.f, 0.f, 0.f, 0.f, 0.f, 0.f};
  for (int j = 0; j < n16; j += 16) {
    int4 i0 = *(const int4*)(it + j);
    int4 i1 = *(const int4*)(it + j + 4);
    int4 i2 = *(const int4*)(it + j + 8);
    int4 i3 = *(const int4*)(it + j + 12);
    u16x8 r0 = *(const u16x8*)(Xh + (size_t)i0.x * 128 + lane * 8);
    u16x8 r1 = *(const u16x8*)(Xh + (size_t)i0.y * 128 + lane * 8);
    u16x8 r2 = *(const u16x8*)(Xh + (size_t)i0.z * 128 + lane * 8);
    u16x8 r3 = *(const u16x8*)(Xh + (size_t)i0.w * 128 + lane * 8);
    u16x8 r4 = *(const u16x8*)(Xh + (size_t)i1.x * 128 + lane * 8);
    u16x8 r5 = *(const u16x8*)(Xh + (size_t)i1.y * 128 + lane * 8);
    u16x8 r6 = *(const u16x8*)(Xh + (size_t)i1.z * 128 + lane * 8);
    u16x8 r7 = *(const u16x8*)(Xh + (size_t)i1.w * 128 + lane * 8);
    u16x8 r8 = *(const u16x8*)(Xh + (size_t)i2.x * 128 + lane * 8);
    u16x8 r9 = *(const u16x8*)(Xh + (size_t)i2.y * 128 + lane * 8);
    u16x8 rA = *(const u16x8*)(Xh + (size_t)i2.z * 128 + lane * 8);
    u16x8 rB = *(const u16x8*)(Xh + (size_t)i2.w * 128 + lane * 8);
    u16x8 rC = *(const u16x8*)(Xh + (size_t)i3.x * 128 + lane * 8);
    u16x8 rD = *(const u16x8*)(Xh + (size_t)i3.y * 128 + lane * 8);
    u16x8 rE = *(const u16x8*)(Xh + (size_t)i3.z * 128 + lane * 8);
    u16x8 rF = *(const u16x8*)(Xh + (size_t)i3.w * 128 + lane * 8);
    #pragma unroll
    for (int q = 0; q < 8; q++) {
      float s0 = (bf2f(r0[q]) + bf2f(r1[q])) + (bf2f(r2[q]) + bf2f(r3[q]));
      float s1 = (bf2f(r4[q]) + bf2f(r5[q])) + (bf2f(r6[q]) + bf2f(r7[q]));
      float s2 = (bf2f(r8[q]) + bf2f(r9[q])) + (bf2f(rA[q]) + bf2f(rB[q]));
      float s3 = (bf2f(rC[q]) + bf2f(rD[q])) + (bf2f(rE[q]) + bf2f(rF[q]));
      acc[q] += (s0 + s1) + (s2 + s3);
    }
  }
  float inv = 1.f / fmaxf((float)cnt, 1.f);
  u16x8 o;
  #pragma unroll
  for (int q = 0; q < 8; q++) o[q] = f2bf(acc[q] * inv);
  *(u16x8*)(Xeh + (size_t)e * 128 + lane * 8) = o;
}

// ---------------- fused vertex_agg + MFMA GEMM, 64-row tile (R12 winner) ----------------
// itemsV is u16 (edge ids < 2^16) -> half the index-list traffic.
// A frag: row = lane&31, k = (lane>>5)*8 + j.  C/D: col = lane&31,
// row = (reg&3) + 8*(reg>>2) + 4*(lane>>5)  [m74/m101-verified]

__global__ __launch_bounds__(256, 5) void gemm_fused(const u16* __restrict__ Xeh,
                                                     const int* __restrict__ cntV,
                                                     const u16* __restrict__ itemsV,
                                                     const u16* __restrict__ x0h,
                                                     const u16* __restrict__ WT,
                                                     u16* __restrict__ Yh, int nrows) {
  __shared__ u16 As[64 * 136];
  int t = threadIdx.x;
  int row0 = blockIdx.x * 64;
  int g = t >> 4, lane = t & 15;
  #pragma unroll
  for (int pass = 0; pass < 4; pass++) {
    int r = pass * 16 + g;
    int v = row0 + r;
    float acc[8] = {0.f, 0.f, 0.f, 0.f, 0.f, 0.f, 0.f, 0.f};
    int cnt = 0;
    if (v < nrows) {
      cnt = cntV[v];
      int n8 = (min(cnt, CAP_V) + 7) & ~7;
      const u16* it = itemsV + (size_t)v * CAP_V;
      for (int j = 0; j < n8; j += 8) {
        u16x8 ei = *(const u16x8*)(it + j);   // 8 edge ids, one 16B load
        u16x8 r0 = *(const u16x8*)(Xeh + (size_t)ei[0] * 128 + lane * 8);
        u16x8 r1 = *(const u16x8*)(Xeh + (size_t)ei[1] * 128 + lane * 8);
        u16x8 r2 = *(const u16x8*)(Xeh + (size_t)ei[2] * 128 + lane * 8);
        u16x8 r3 = *(const u16x8*)(Xeh + (size_t)ei[3] * 128 + lane * 8);
        u16x8 r4 = *(const u16x8*)(Xeh + (size_t)ei[4] * 128 + lane * 8);
        u16x8 r5 = *(const u16x8*)(Xeh + (size_t)ei[5] * 128 + lane * 8);
        u16x8 r6 = *(const u16x8*)(Xeh + (size_t)ei[6] * 128 + lane * 8);
        u16x8 r7 = *(const u16x8*)(Xeh + (size_t)ei[7] * 128 + lane * 8);
        #pragma unroll
        for (int q = 0; q < 8; q++)
          acc[q] += ((bf2f(r0[q]) + bf2f(r1[q])) + (bf2f(r2[q]) + bf2f(r3[q]))) +
                    ((bf2f(r4[q]) + bf2f(r5[q])) + (bf2f(r6[q]) + bf2f(r7[q])));
      }
    }
    float inv = 1.f / fmaxf((float)cnt, 1.f);
    float sq = 0.f;
    #pragma unroll
    for (int q = 0; q < 8; q++) { acc[q] *= inv; sq += acc[q] * acc[q]; }
    sq += __shfl_xor(sq, 1, 64);
    sq += __shfl_xor(sq, 2, 64);
    sq += __shfl_xor(sq, 4, 64);
    sq += __shfl_xor(sq, 8, 64);
    float scale = (sq > 0.f) ? rsqrtf(sq) : 0.f;
    u16x8 o = {0, 0, 0, 0, 0, 0, 0, 0};
    if (v < nrows) {
      u16x8 x0v = *(const u16x8*)(x0h + (size_t)v * 128 + lane * 8);
      #pragma unroll
      for (int q = 0; q < 8; q++)
        o[q] = f2bf(0.9f * acc[q] * scale + 0.1f * bf2f(x0v[q]));
    }
    *(u16x8*)&As[r * 136 + lane * 8] = o;
  }
  __syncthreads();

  int w = t >> 6, lane64 = t & 63;
  int l31 = lane64 & 31, kh = lane64 >> 5;
  int wr = w >> 1, wc = w & 1;
  floatx16 acc[2];
  #pragma unroll
  for (int ct = 0; ct < 2; ct++)
    #pragma unroll
    for (int q = 0; q < 16; q++) acc[ct][q] = 0.f;

  const u16* wtb0 = WT + (size_t)(wc * 64 + l31) * 128;
  const u16* wtb1 = WT + (size_t)(wc * 64 + 32 + l31) * 128;
  #pragma unroll
  for (int ks = 0; ks < 8; ks++) {
    int koff = ks * 16 + kh * 8;
    short8 b0 = *(const short8*)(wtb0 + koff);
    short8 b1 = *(const short8*)(wtb1 + koff);
    short8 a0 = *(const short8*)&As[(wr * 32 + l31) * 136 + koff];
    acc[0] = __builtin_amdgcn_mfma_f32_32x32x16_bf16(a0, b0, acc[0], 0, 0, 0);
    acc[1] = __builtin_amdgcn_mfma_f32_32x32x16_bf16(a0, b1, acc[1], 0, 0, 0);
  }
  __syncthreads();

  #pragma unroll
  for (int ct = 0; ct < 2; ct++) {
    int col = wc * 64 + ct * 32 + l31;
    #pragma unroll
    for (int reg = 0; reg < 16; reg++) {
      int row = wr * 32 + (reg & 3) + 8 * (reg >> 2) + 4 * kh;
      As[row * 136 + col] = f2bf(fmaxf(acc[ct][reg], 0.f));
    }
  }
  __syncthreads();
  #pragma unroll
  for (int i = 0; i < 4; i++) {
    int idx = t + 256 * i;
    int r = idx >> 4, c8 = idx & 15;
    if (row0 + r < nrows)
      *(u16x8*)(Yh + (size_t)(row0 + r) * 128 + c8 * 8) =
          *(const u16x8*)&As[r * 136 + c8 * 8];
  }
}

// first GEMM: fp32 A in, +bias, relu, dual bf16 outputs; B from global
__global__ __launch_bounds__(256, 4) void gemm_first(const float* __restrict__ A,
                                                     const u16* __restrict__ WT,
                                                     const float* __restrict__ bias,
                                                     u16* __restrict__ Yh,
                                                     u16* __restrict__ Y2h, int nrows) {
  __shared__ u16 As[128 * 136];
  int t = threadIdx.x;
  int row0 = blockIdx.x * 128;
  #pragma unroll
  for (int i = 0; i < 8; i++) {
    int idx = t + 256 * i;
    int r = idx >> 4, c8 = idx & 15;
    u16x8 v = {0, 0, 0, 0, 0, 0, 0, 0};
    if (row0 + r < nrows) {
      const float* p = A + (size_t)(row0 + r) * 128 + c8 * 8;
      float4 a = *(const float4*)p;
      float4 b = *(const float4*)(p + 4);
      v[0] = f2bf(a.x); v[1] = f2bf(a.y); v[2] = f2bf(a.z); v[3] = f2bf(a.w);
      v[4] = f2bf(b.x); v[5] = f2bf(b.y); v[6] = f2bf(b.z); v[7] = f2bf(b.w);
    }
    *(u16x8*)&As[r * 136 + c8 * 8] = v;
  }
  __syncthreads();

  int w = t >> 6, lane = t & 63;
  int l31 = lane & 31, kh = lane >> 5;
  int wr = w >> 1, wc = w & 1;
  floatx16 acc[2][2];
  #pragma unroll
  for (int rt = 0; rt < 2; rt++)
    #pragma unroll
    for (int ct = 0; ct < 2; ct++)
      #pragma unroll
      for (int q = 0; q < 16; q++) acc[rt][ct][q] = 0.f;

  const u16* wtb0 = WT + (size_t)(wc * 64 + l31) * 128;
  const u16* wtb1 = WT + (size_t)(wc * 64 + 32 + l31) * 128;
  #pragma unroll
  for (int ks = 0; ks < 8; ks++) {
    int koff = ks * 16 + kh * 8;
    short8 b0 = *(const short8*)(wtb0 + koff);
    short8 b1 = *(const short8*)(wtb1 + koff);
    short8 a0 = *(const short8*)&As[(wr * 64 + l31) * 136 + koff];
    short8 a1 = *(const short8*)&As[(wr * 64 + 32 + l31) * 136 + koff];
    acc[0][0] = __builtin_amdgcn_mfma_f32_32x32x16_bf16(a0, b0, acc[0][0], 0, 0, 0);
    acc[0][1] = __builtin_amdgcn_mfma_f32_32x32x16_bf16(a0, b1, acc[0][1], 0, 0, 0);
    acc[1][0] = __builtin_amdgcn_mfma_f32_32x32x16_bf16(a1, b0, acc[1][0], 0, 0, 0);
    acc[1][1] = __builtin_amdgcn_mfma_f32_32x32x16_bf16(a1, b1, acc[1][1], 0, 0, 0);
  }
  __syncthreads();

  #pragma unroll
  for (int rt = 0; rt < 2; rt++)
    #pragma unroll
    for (int ct = 0; ct < 2; ct++) {
      int col = wc * 64 + ct * 32 + l31;
      float bv = bias[col];
      #pragma unroll
      for (int reg = 0; reg < 16; reg++) {
        int row = wr * 64 + rt * 32 + (reg & 3) + 8 * (reg >> 2) + 4 * kh;
        As[row * 136 + col] = f2bf(fmaxf(acc[rt][ct][reg] + bv, 0.f));
      }
    }
  __syncthreads();
  #pragma unroll
  for (int i = 0; i < 8; i++) {
    int idx = t + 256 * i;
    int r = idx >> 4, c8 = idx & 15;
    if (row0 + r < nrows) {
      u16x8 v = *(const u16x8*)&As[r * 136 + c8 * 8];
      *(u16x8*)(Yh + (size_t)(row0 + r) * 128 + c8 * 8) = v;
      *(u16x8*)(Y2h + (size_t)(row0 + r) * 128 + c8 * 8) = v;
    }
  }
}

// ---------------- output GEMM: out[nrows,40] = Xh @ Wout + bout ----------------

__global__ __launch_bounds__(256) void gemm_out(const u16* __restrict__ Xh,
                                                const float* __restrict__ W,
                                                const float* __restrict__ bias,
                                                float* __restrict__ Y, int nrows) {
  __shared__ float xs[128][36];
  __shared__ float ws[32][44];
  int t = threadIdx.x;
  int tr = t >> 3;
  int tc = t & 7;
  int row0 = blockIdx.x * 128;
  float acc[4][5];
  #pragma unroll
  for (int i = 0; i < 4; i++)
    #pragma unroll
    for (int j = 0; j < 5; j++) acc[i][j] = 0.f;

  for (int k0 = 0; k0 < 128; k0 += 32) {
    #pragma unroll
    for (int i = 0; i < 2; i++) {
      int idx = t + 256 * i;
      int r = idx >> 2, c8 = idx & 3;
      int gr = row0 + r;
      u16x8 v = {0, 0, 0, 0, 0, 0, 0, 0};
      if (gr < nrows) v = *(const u16x8*)(Xh + (size_t)gr * 128 + k0 + c8 * 8);
      #pragma unroll
      for (int q = 0; q < 8; q++) xs[r][c8 * 8 + q] = bf2f(v[q]);
    }
    #pragma unroll
    for (int i = 0; i < 5; i++) {
      int idx = t + 256 * i;
      int r = idx / 40, c = idx % 40;
      ws[r][c] = W[(k0 + r) * 40 + c];
    }
    __syncthreads();
    #pragma unroll
    for (int kk4 = 0; kk4 < 8; kk4++) {
      float4 xv[4];
      #pragma unroll
      for (int i = 0; i < 4; i++) xv[i] = *(const float4*)&xs[tr + 32 * i][kk4 * 4];
      #pragma unroll
      for (int q = 0; q < 4; q++) {
        int kk = kk4 * 4 + q;
        float wv[5];
        #pragma unroll
        for (int j = 0; j < 5; j++) wv[j] = ws[kk][tc * 5 + j];
        #pragma unroll
        for (int i = 0; i < 4; i++) {
          float xq = ((const float*)&xv[i])[q];
          #pragma unroll
          for (int j = 0; j < 5; j++) acc[i][j] += xq * wv[j];
        }
      }
    }
    __syncthreads();
  }
  #pragma unroll
  for (int i = 0; i < 4; i++) {
    int gr = row0 + tr + 32 * i;
    if (gr >= nrows) continue;
    #pragma unroll
    for (int j = 0; j < 5; j++) {
      int c = tc * 5 + j;
      Y[(long)gr * 40 + c] = acc[i][j] + bias[c];
    }
  }
}

// ---------------- launch ----------------

extern "C" void kernel_launch(void* const* d_in, const int* in_sizes, int n_in,
                              void* d_out, int out_size, void* d_ws, size_t ws_size,
                              hipStream_t stream) {
  const float* x    = (const float*)d_in[0];
  const float* W0   = (const float*)d_in[1];
  const float* b0   = (const float*)d_in[2];
  const float* Ws   = (const float*)d_in[3];
  const float* Wout = (const float*)d_in[4];
  const float* bout = (const float*)d_in[5];
  const int* vertex = (const int*)d_in[6];
  const int* edges  = (const int*)d_in[7];
  float* out = (float*)d_out;

  char* base = (char*)d_ws;
  size_t o = 0;
  auto alloc = [&](size_t bytes) -> char* {
    char* r = base + o;
    o += (bytes + 255) & ~(size_t)255;
    return r;
  };
  u16* x_curh = (u16*)alloc((size_t)(NV + 1) * 128 * 2);  // +1 dummy zero row
  u16* x0h    = (u16*)alloc((size_t)NV * 128 * 2);
  u16* Xeh    = (u16*)alloc((size_t)(NE + 1) * 128 * 2);  // +1 dummy zero row
  u16* WT     = (u16*)alloc((size_t)5 * 16384 * 2);
  int* cntE   = (int*)alloc((size_t)NE * 4);
  int* cntV   = (int*)alloc((size_t)NV * 4);
  int* itemsE = (int*)alloc((size_t)NE * CAP_E * 4);
  u16* itemsV = (u16*)alloc((size_t)NV * CAP_V * 2);      // u16 edge ids
  uint32* pairE = (uint32*)alloc((size_t)NB_E * CAPB_E * 4);
  uint32* pairV = (uint32*)alloc((size_t)NB_V * CAPB_V * 4);
  uint2* ovfE  = (uint2*)alloc((size_t)OVF_CAP * 8);
  uint2* ovfV  = (uint2*)alloc((size_t)OVF_CAP * 8);
  int* curAll = (int*)alloc((size_t)(NB_E + NB_V + 2) * 4);
  int* curE = curAll;
  int* curV = curAll + NB_E;
  int* ovfCnt = curAll + NB_E + NB_V;

  int nzero = NB_E + NB_V + 2;
  zero_misc<<<(nzero + 255) / 256, 256, 0, stream>>>(curAll, nzero,
                                                     x_curh + (size_t)NV * 128,
                                                     Xeh + (size_t)NE * 128);
  scatter_binned<<<N_TILES, 256, 0, stream>>>(vertex, edges, curE, curV, ovfCnt,
                                              pairE, pairV, ovfE, ovfV);
  expand<<<NB_E, 256, 0, stream>>>(pairE, curE, CAPB_E, ovfE, ovfCnt,
                                   itemsE, CAP_E, cntE, NE, 16, NV);
  expand16<<<NB_V, 256, 0, stream>>>(pairV, curV, CAPB_V, ovfV, ovfCnt + 1,
                                     itemsV, CAP_V, cntV, NV, 8, NE);
  prep_weights<<<(5 * 16384 + 255) / 256, 256, 0, stream>>>(W0, Ws, WT);

  int gblocks = (NV + 127) / 128;
  int fblocks = (NV + 63) / 64;
  gemm_first<<<gblocks, 256, 0, stream>>>(x, WT, b0, x_curh, x0h, NV);

  for (int i = 0; i < 4; i++) {
    edge_agg<<<NE / 16, 256, 0, stream>>>(x_curh, cntE, itemsE, Xeh);
    gemm_fused<<<fblocks, 256, 0, stream>>>(Xeh, cntV, itemsV, x0h,
                                            WT + (size_t)(1 + i) * 16384, x_curh, NV);
  }
  gemm_out<<<gblocks, 256, 0, stream>>>(x_curh, Wout, bout, out, NV);
}

// Round 15
// 481.952 us; speedup vs baseline: 1.3063x; 1.0132x over previous
//
#include <hip/hip_runtime.h>

#define NV 100000
#define NE 50000
#define NNZ_C 800000
#define CAP_E 64        // slots per edge   (multiple of 16)
#define CAP_V 48        // slots per vertex (multiple of 8)
#define NB_E 391        // ceil(NE/128)
#define NB_V 782        // ceil(NV/128)
#define CAPB_E 2560
#define CAPB_V 1408
#define OVF_CAP 810000
#define T_ITEMS 4096
#define N_TILES ((NNZ_C + T_ITEMS - 1) / T_ITEMS)   // 196

typedef unsigned int uint32;
typedef unsigned short u16;
typedef u16 u16x8 __attribute__((ext_vector_type(8)));
typedef short short8 __attribute__((ext_vector_type(8)));
typedef float floatx16 __attribute__((ext_vector_type(16)));

__device__ __forceinline__ float bf2f(u16 h) {
  return __uint_as_float(((uint32)h) << 16);
}
__device__ __forceinline__ u16 f2bf(float f) {
  uint32 u = __float_as_uint(f);
  u += 0x7FFF + ((u >> 16) & 1);   // RNE
  return (u16)(u >> 16);
}

// ---------------- zero cursors + dummy gather rows ----------------

__global__ void zero_misc(int* __restrict__ cur, int n,
                          u16* __restrict__ dummyX, u16* __restrict__ dummyXe) {
  int i = blockIdx.x * blockDim.x + threadIdx.x;
  if (i < n) cur[i] = 0;
  if (i < 128) { dummyX[i] = 0; dummyXe[i] = 0; }
}

// ---------------- LDS-binned scatter ----------------

__global__ __launch_bounds__(256) void scatter_binned(const int* __restrict__ vertex,
                                                      const int* __restrict__ edges,
                                                      int* __restrict__ curE,
                                                      int* __restrict__ curV,
                                                      int* __restrict__ ovfCnt,
                                                      uint32* __restrict__ pairE,
                                                      uint32* __restrict__ pairV,
                                                      uint2* __restrict__ ovfE,
                                                      uint2* __restrict__ ovfV) {
  __shared__ int histE[NB_E], baseE[NB_E];
  __shared__ int histV[NB_V], baseV[NB_V];
  int t = threadIdx.x;
  for (int tile = blockIdx.x; tile < N_TILES; tile += gridDim.x) {
    for (int b = t; b < NB_E; b += 256) histE[b] = 0;
    for (int b = t; b < NB_V; b += 256) histV[b] = 0;
    __syncthreads();
    int base = tile * T_ITEMS;
    int ev[16], vv[16], rE[16], rV[16];
    #pragma unroll
    for (int i = 0; i < 16; i++) {
      int k = base + t + i * 256;
      if (k < NNZ_C) {
        ev[i] = edges[k];
        vv[i] = vertex[k];
        rE[i] = atomicAdd(&histE[ev[i] >> 7], 1);
        rV[i] = atomicAdd(&histV[vv[i] >> 7], 1);
      }
    }
    __syncthreads();
    for (int b = t; b < NB_E; b += 256) {
      int h = histE[b];
      baseE[b] = h ? atomicAdd(&curE[b], h) : 0;
    }
    for (int b = t; b < NB_V; b += 256) {
      int h = histV[b];
      baseV[b] = h ? atomicAdd(&curV[b], h) : 0;
    }
    __syncthreads();
    #pragma unroll
    for (int i = 0; i < 16; i++) {
      int k = base + t + i * 256;
      if (k < NNZ_C) {
        uint32 e = (uint32)ev[i], v = (uint32)vv[i];
        uint32 pkE = ((e & 127u) << 25) | v;
        uint32 pkV = ((v & 127u) << 25) | e;
        int pE = baseE[e >> 7] + rE[i];
        if (pE < CAPB_E) pairE[(size_t)(e >> 7) * CAPB_E + pE] = pkE;
        else { int op = atomicAdd(&ovfCnt[0], 1); if (op < OVF_CAP) ovfE[op] = make_uint2(e >> 7, pkE); }
        int pV = baseV[v >> 7] + rV[i];
        if (pV < CAPB_V) pairV[(size_t)(v >> 7) * CAPB_V + pV] = pkV;
        else { int op = atomicAdd(&ovfCnt[1], 1); if (op < OVF_CAP) ovfV[op] = make_uint2(v >> 7, pkV); }
      }
    }
    __syncthreads();
  }
}

// one block per bucket: rank via LDS atomics; pad each key list to multiple of P
__global__ __launch_bounds__(256) void expand(const uint32* __restrict__ pairs,
                                              const int* __restrict__ cur, int capb,
                                              const uint2* __restrict__ ovf,
                                              const int* __restrict__ ovfCnt,
                                              int* __restrict__ items, int cap,
                                              int* __restrict__ cnt, int nKeys,
                                              int P, int dummy) {
  __shared__ int lcnt[128];
  int b = blockIdx.x, t = threadIdx.x;
  if (t < 128) lcnt[t] = 0;
  __syncthreads();
  int n = min(cur[b], capb);
  const uint32* p = pairs + (size_t)b * capb;
  for (int i = t; i < n; i += 256) {
    uint32 w = p[i];
    int loc = w >> 25;
    int val = (int)(w & 0x1FFFFFFu);
    int r = atomicAdd(&lcnt[loc], 1);
    if (r < cap) items[(size_t)((b << 7) + loc) * cap + r] = val;
  }
  int novf = min(*ovfCnt, OVF_CAP);
  for (int i = t; i < novf; i += 256) {
    uint2 w = ovf[i];
    if ((int)w.x == b) {
      int loc = w.y >> 25;
      int val = (int)(w.y & 0x1FFFFFFu);
      int r = atomicAdd(&lcnt[loc], 1);
      if (r < cap) items[(size_t)((b << 7) + loc) * cap + r] = val;
    }
  }
  __syncthreads();
  if (t < 128) {
    int key = (b << 7) + t;
    if (key < nKeys) {
      int c = lcnt[t];
      cnt[key] = c;
      int cc = min(c, cap);
      int padded = min((cc + P - 1) & ~(P - 1), cap);
      for (int r = cc; r < padded; r++)
        items[(size_t)key * cap + r] = dummy;
    }
  }
}

// ---------------- weight prep ----------------
// WT: [0,16384) = W0T[n][k]; then 4x WeffT[i][n][k], Weff=(1-b)I+b*Ws[i]

__global__ void prep_weights(const float* __restrict__ W0, const float* __restrict__ Ws,
                             u16* __restrict__ WT) {
  int idx = blockIdx.x * blockDim.x + threadIdx.x;
  if (idx >= 5 * 16384) return;
  const float betas[4] = {0.4054651081f, 0.2231435513f, 0.1541506798f, 0.1177830357f};
  int sec = idx >> 14;
  int rc = idx & 16383;
  int n = rc >> 7, k = rc & 127;
  float v;
  if (sec == 0) {
    v = W0[k * 128 + n];
  } else {
    int i = sec - 1;
    float b = betas[i];
    v = b * Ws[i * 16384 + k * 128 + n];
    if (k == n) v += 1.0f - b;
  }
  WT[idx] = f2bf(v);
}

// ---------------- edge aggregation (bf16, 16 lanes/row, guard-free) ----------------

__global__ __launch_bounds__(256) void edge_agg(const u16* __restrict__ Xh,
                                                const int* __restrict__ cntE,
                                                const int* __restrict__ itemsE,
                                                u16* __restrict__ Xeh) {
  int g = threadIdx.x >> 4;
  int lane = threadIdx.x & 15;
  int e = blockIdx.x * 16 + g;
  int cnt = cntE[e];
  int n16 = (min(cnt, CAP_E) + 15) & ~15;
  const int* it = itemsE + (size_t)e * CAP_E;
  float acc[8] = {0.f, 0.f, 0.f, 0.f, 0.f, 0.f, 0.f, 0.f};
  for (int j = 0; j < n16; j += 16) {
    int4 i0 = *(const int4*)(it + j);
    int4 i1 = *(const int4*)(it + j + 4);
    int4 i2 = *(const int4*)(it + j + 8);
    int4 i3 = *(const int4*)(it + j + 12);
    u16x8 r0 = *(const u16x8*)(Xh + (size_t)i0.x * 128 + lane * 8);
    u16x8 r1 = *(const u16x8*)(Xh + (size_t)i0.y * 128 + lane * 8);
    u16x8 r2 = *(const u16x8*)(Xh + (size_t)i0.z * 128 + lane * 8);
    u16x8 r3 = *(const u16x8*)(Xh + (size_t)i0.w * 128 + lane * 8);
    u16x8 r4 = *(const u16x8*)(Xh + (size_t)i1.x * 128 + lane * 8);
    u16x8 r5 = *(const u16x8*)(Xh + (size_t)i1.y * 128 + lane * 8);
    u16x8 r6 = *(const u16x8*)(Xh + (size_t)i1.z * 128 + lane * 8);
    u16x8 r7 = *(const u16x8*)(Xh + (size_t)i1.w * 128 + lane * 8);
    u16x8 r8 = *(const u16x8*)(Xh + (size_t)i2.x * 128 + lane * 8);
    u16x8 r9 = *(const u16x8*)(Xh + (size_t)i2.y * 128 + lane * 8);
    u16x8 rA = *(const u16x8*)(Xh + (size_t)i2.z * 128 + lane * 8);
    u16x8 rB = *(const u16x8*)(Xh + (size_t)i2.w * 128 + lane * 8);
    u16x8 rC = *(const u16x8*)(Xh + (size_t)i3.x * 128 + lane * 8);
    u16x8 rD = *(const u16x8*)(Xh + (size_t)i3.y * 128 + lane * 8);
    u16x8 rE = *(const u16x8*)(Xh + (size_t)i3.z * 128 + lane * 8);
    u16x8 rF = *(const u16x8*)(Xh + (size_t)i3.w * 128 + lane * 8);
    #pragma unroll
    for (int q = 0; q < 8; q++) {
      float s0 = (bf2f(r0[q]) + bf2f(r1[q])) + (bf2f(r2[q]) + bf2f(r3[q]));
      float s1 = (bf2f(r4[q]) + bf2f(r5[q])) + (bf2f(r6[q]) + bf2f(r7[q]));
      float s2 = (bf2f(r8[q]) + bf2f(r9[q])) + (bf2f(rA[q]) + bf2f(rB[q]));
      float s3 = (bf2f(rC[q]) + bf2f(rD[q])) + (bf2f(rE[q]) + bf2f(rF[q]));
      acc[q] += (s0 + s1) + (s2 + s3);
    }
  }
  float inv = 1.f / fmaxf((float)cnt, 1.f);
  u16x8 o;
  #pragma unroll
  for (int q = 0; q < 8; q++) o[q] = f2bf(acc[q] * inv);
  *(u16x8*)(Xeh + (size_t)e * 128 + lane * 8) = o;
}

// ---------------- fused vertex_agg + MFMA GEMM, 64-row tile (R12 winner) ----------------
// A frag: row = lane&31, k = (lane>>5)*8 + j.  C/D: col = lane&31,
// row = (reg&3) + 8*(reg>>2) + 4*(lane>>5)  [m74/m101-verified]

__global__ __launch_bounds__(256, 5) void gemm_fused(const u16* __restrict__ Xeh,
                                                     const int* __restrict__ cntV,
                                                     const int* __restrict__ itemsV,
                                                     const u16* __restrict__ x0h,
                                                     const u16* __restrict__ WT,
                                                     u16* __restrict__ Yh, int nrows) {
  __shared__ u16 As[64 * 136];
  int t = threadIdx.x;
  int row0 = blockIdx.x * 64;
  int g = t >> 4, lane = t & 15;
  #pragma unroll
  for (int pass = 0; pass < 4; pass++) {
    int r = pass * 16 + g;
    int v = row0 + r;
    float acc[8] = {0.f, 0.f, 0.f, 0.f, 0.f, 0.f, 0.f, 0.f};
    int cnt = 0;
    if (v < nrows) {
      cnt = cntV[v];
      int n8 = (min(cnt, CAP_V) + 7) & ~7;
      const int* it = itemsV + (size_t)v * CAP_V;
      for (int j = 0; j < n8; j += 8) {
        int4 e0 = *(const int4*)(it + j);
        int4 e1 = *(const int4*)(it + j + 4);
        u16x8 r0 = *(const u16x8*)(Xeh + (size_t)e0.x * 128 + lane * 8);
        u16x8 r1 = *(const u16x8*)(Xeh + (size_t)e0.y * 128 + lane * 8);
        u16x8 r2 = *(const u16x8*)(Xeh + (size_t)e0.z * 128 + lane * 8);
        u16x8 r3 = *(const u16x8*)(Xeh + (size_t)e0.w * 128 + lane * 8);
        u16x8 r4 = *(const u16x8*)(Xeh + (size_t)e1.x * 128 + lane * 8);
        u16x8 r5 = *(const u16x8*)(Xeh + (size_t)e1.y * 128 + lane * 8);
        u16x8 r6 = *(const u16x8*)(Xeh + (size_t)e1.z * 128 + lane * 8);
        u16x8 r7 = *(const u16x8*)(Xeh + (size_t)e1.w * 128 + lane * 8);
        #pragma unroll
        for (int q = 0; q < 8; q++)
          acc[q] += ((bf2f(r0[q]) + bf2f(r1[q])) + (bf2f(r2[q]) + bf2f(r3[q]))) +
                    ((bf2f(r4[q]) + bf2f(r5[q])) + (bf2f(r6[q]) + bf2f(r7[q])));
      }
    }
    float inv = 1.f / fmaxf((float)cnt, 1.f);
    float sq = 0.f;
    #pragma unroll
    for (int q = 0; q < 8; q++) { acc[q] *= inv; sq += acc[q] * acc[q]; }
    sq += __shfl_xor(sq, 1, 64);
    sq += __shfl_xor(sq, 2, 64);
    sq += __shfl_xor(sq, 4, 64);
    sq += __shfl_xor(sq, 8, 64);
    float scale = (sq > 0.f) ? rsqrtf(sq) : 0.f;
    u16x8 o = {0, 0, 0, 0, 0, 0, 0, 0};
    if (v < nrows) {
      u16x8 x0v = *(const u16x8*)(x0h + (size_t)v * 128 + lane * 8);
      #pragma unroll
      for (int q = 0; q < 8; q++)
        o[q] = f2bf(0.9f * acc[q] * scale + 0.1f * bf2f(x0v[q]));
    }
    *(u16x8*)&As[r * 136 + lane * 8] = o;
  }
  __syncthreads();

  int w = t >> 6, lane64 = t & 63;
  int l31 = lane64 & 31, kh = lane64 >> 5;
  int wr = w >> 1, wc = w & 1;
  floatx16 acc[2];
  #pragma unroll
  for (int ct = 0; ct < 2; ct++)
    #pragma unroll
    for (int q = 0; q < 16; q++) acc[ct][q] = 0.f;

  const u16* wtb0 = WT + (size_t)(wc * 64 + l31) * 128;
  const u16* wtb1 = WT + (size_t)(wc * 64 + 32 + l31) * 128;
  #pragma unroll
  for (int ks = 0; ks < 8; ks++) {
    int koff = ks * 16 + kh * 8;
    short8 b0 = *(const short8*)(wtb0 + koff);
    short8 b1 = *(const short8*)(wtb1 + koff);
    short8 a0 = *(const short8*)&As[(wr * 32 + l31) * 136 + koff];
    acc[0] = __builtin_amdgcn_mfma_f32_32x32x16_bf16(a0, b0, acc[0], 0, 0, 0);
    acc[1] = __builtin_amdgcn_mfma_f32_32x32x16_bf16(a0, b1, acc[1], 0, 0, 0);
  }
  __syncthreads();

  #pragma unroll
  for (int ct = 0; ct < 2; ct++) {
    int col = wc * 64 + ct * 32 + l31;
    #pragma unroll
    for (int reg = 0; reg < 16; reg++) {
      int row = wr * 32 + (reg & 3) + 8 * (reg >> 2) + 4 * kh;
      As[row * 136 + col] = f2bf(fmaxf(acc[ct][reg], 0.f));
    }
  }
  __syncthreads();
  #pragma unroll
  for (int i = 0; i < 4; i++) {
    int idx = t + 256 * i;
    int r = idx >> 4, c8 = idx & 15;
    if (row0 + r < nrows)
      *(u16x8*)(Yh + (size_t)(row0 + r) * 128 + c8 * 8) =
          *(const u16x8*)&As[r * 136 + c8 * 8];
  }
}

// first GEMM: fp32 A in, +bias, relu, dual bf16 outputs; B from global
__global__ __launch_bounds__(256, 4) void gemm_first(const float* __restrict__ A,
                                                     const u16* __restrict__ WT,
                                                     const float* __restrict__ bias,
                                                     u16* __restrict__ Yh,
                                                     u16* __restrict__ Y2h, int nrows) {
  __shared__ u16 As[128 * 136];
  int t = threadIdx.x;
  int row0 = blockIdx.x * 128;
  #pragma unroll
  for (int i = 0; i < 8; i++) {
    int idx = t + 256 * i;
    int r = idx >> 4, c8 = idx & 15;
    u16x8 v = {0, 0, 0, 0, 0, 0, 0, 0};
    if (row0 + r < nrows) {
      const float* p = A + (size_t)(row0 + r) * 128 + c8 * 8;
      float4 a = *(const float4*)p;
      float4 b = *(const float4*)(p + 4);
      v[0] = f2bf(a.x); v[1] = f2bf(a.y); v[2] = f2bf(a.z); v[3] = f2bf(a.w);
      v[4] = f2bf(b.x); v[5] = f2bf(b.y); v[6] = f2bf(b.z); v[7] = f2bf(b.w);
    }
    *(u16x8*)&As[r * 136 + c8 * 8] = v;
  }
  __syncthreads();

  int w = t >> 6, lane = t & 63;
  int l31 = lane & 31, kh = lane >> 5;
  int wr = w >> 1, wc = w & 1;
  floatx16 acc[2][2];
  #pragma unroll
  for (int rt = 0; rt < 2; rt++)
    #pragma unroll
    for (int ct = 0; ct < 2; ct++)
      #pragma unroll
      for (int q = 0; q < 16; q++) acc[rt][ct][q] = 0.f;

  const u16* wtb0 = WT + (size_t)(wc * 64 + l31) * 128;
  const u16* wtb1 = WT + (size_t)(wc * 64 + 32 + l31) * 128;
  #pragma unroll
  for (int ks = 0; ks < 8; ks++) {
    int koff = ks * 16 + kh * 8;
    short8 b0 = *(const short8*)(wtb0 + koff);
    short8 b1 = *(const short8*)(wtb1 + koff);
    short8 a0 = *(const short8*)&As[(wr * 64 + l31) * 136 + koff];
    short8 a1 = *(const short8*)&As[(wr * 64 + 32 + l31) * 136 + koff];
    acc[0][0] = __builtin_amdgcn_mfma_f32_32x32x16_bf16(a0, b0, acc[0][0], 0, 0, 0);
    acc[0][1] = __builtin_amdgcn_mfma_f32_32x32x16_bf16(a0, b1, acc[0][1], 0, 0, 0);
    acc[1][0] = __builtin_amdgcn_mfma_f32_32x32x16_bf16(a1, b0, acc[1][0], 0, 0, 0);
    acc[1][1] = __builtin_amdgcn_mfma_f32_32x32x16_bf16(a1, b1, acc[1][1], 0, 0, 0);
  }
  __syncthreads();

  #pragma unroll
  for (int rt = 0; rt < 2; rt++)
    #pragma unroll
    for (int ct = 0; ct < 2; ct++) {
      int col = wc * 64 + ct * 32 + l31;
      float bv = bias[col];
      #pragma unroll
      for (int reg = 0; reg < 16; reg++) {
        int row = wr * 64 + rt * 32 + (reg & 3) + 8 * (reg >> 2) + 4 * kh;
        As[row * 136 + col] = f2bf(fmaxf(acc[rt][ct][reg] + bv, 0.f));
      }
    }
  __syncthreads();
  #pragma unroll
  for (int i = 0; i < 8; i++) {
    int idx = t + 256 * i;
    int r = idx >> 4, c8 = idx & 15;
    if (row0 + r < nrows) {
      u16x8 v = *(const u16x8*)&As[r * 136 + c8 * 8];
      *(u16x8*)(Yh + (size_t)(row0 + r) * 128 + c8 * 8) = v;
      *(u16x8*)(Y2h + (size_t)(row0 + r) * 128 + c8 * 8) = v;
    }
  }
}

// ---------------- output GEMM: out[nrows,40] = Xh @ Wout + bout ----------------

__global__ __launch_bounds__(256) void gemm_out(const u16* __restrict__ Xh,
                                                const float* __restrict__ W,
                                                const float* __restrict__ bias,
                                                float* __restrict__ Y, int nrows) {
  __shared__ float xs[128][36];
  __shared__ float ws[32][44];
  int t = threadIdx.x;
  int tr = t >> 3;
  int tc = t & 7;
  int row0 = blockIdx.x * 128;
  float acc[4][5];
  #pragma unroll
  for (int i = 0; i < 4; i++)
    #pragma unroll
    for (int j = 0; j < 5; j++) acc[i][j] = 0.f;

  for (int k0 = 0; k0 < 128; k0 += 32) {
    #pragma unroll
    for (int i = 0; i < 2; i++) {
      int idx = t + 256 * i;
      int r = idx >> 2, c8 = idx & 3;
      int gr = row0 + r;
      u16x8 v = {0, 0, 0, 0, 0, 0, 0, 0};
      if (gr < nrows) v = *(const u16x8*)(Xh + (size_t)gr * 128 + k0 + c8 * 8);
      #pragma unroll
      for (int q = 0; q < 8; q++) xs[r][c8 * 8 + q] = bf2f(v[q]);
    }
    #pragma unroll
    for (int i = 0; i < 5; i++) {
      int idx = t + 256 * i;
      int r = idx / 40, c = idx % 40;
      ws[r][c] = W[(k0 + r) * 40 + c];
    }
    __syncthreads();
    #pragma unroll
    for (int kk4 = 0; kk4 < 8; kk4++) {
      float4 xv[4];
      #pragma unroll
      for (int i = 0; i < 4; i++) xv[i] = *(const float4*)&xs[tr + 32 * i][kk4 * 4];
      #pragma unroll
      for (int q = 0; q < 4; q++) {
        int kk = kk4 * 4 + q;
        float wv[5];
        #pragma unroll
        for (int j = 0; j < 5; j++) wv[j] = ws[kk][tc * 5 + j];
        #pragma unroll
        for (int i = 0; i < 4; i++) {
          float xq = ((const float*)&xv[i])[q];
          #pragma unroll
          for (int j = 0; j < 5; j++) acc[i][j] += xq * wv[j];
        }
      }
    }
    __syncthreads();
  }
  #pragma unroll
  for (int i = 0; i < 4; i++) {
    int gr = row0 + tr + 32 * i;
    if (gr >= nrows) continue;
    #pragma unroll
    for (int j = 0; j < 5; j++) {
      int c = tc * 5 + j;
      Y[(long)gr * 40 + c] = acc[i][j] + bias[c];
    }
  }
}

// ---------------- launch ----------------

extern "C" void kernel_launch(void* const* d_in, const int* in_sizes, int n_in,
                              void* d_out, int out_size, void* d_ws, size_t ws_size,
                              hipStream_t stream) {
  const float* x    = (const float*)d_in[0];
  const float* W0   = (const float*)d_in[1];
  const float* b0   = (const float*)d_in[2];
  const float* Ws   = (const float*)d_in[3];
  const float* Wout = (const float*)d_in[4];
  const float* bout = (const float*)d_in[5];
  const int* vertex = (const int*)d_in[6];
  const int* edges  = (const int*)d_in[7];
  float* out = (float*)d_out;

  char* base = (char*)d_ws;
  size_t o = 0;
  auto alloc = [&](size_t bytes) -> char* {
    char* r = base + o;
    o += (bytes + 255) & ~(size_t)255;
    return r;
  };
  u16* x_curh = (u16*)alloc((size_t)(NV + 1) * 128 * 2);  // +1 dummy zero row
  u16* x0h    = (u16*)alloc((size_t)NV * 128 * 2);
  u16* Xeh    = (u16*)alloc((size_t)(NE + 1) * 128 * 2);  // +1 dummy zero row
  u16* WT     = (u16*)alloc((size_t)5 * 16384 * 2);
  int* cntE   = (int*)alloc((size_t)NE * 4);
  int* cntV   = (int*)alloc((size_t)NV * 4);
  int* itemsE = (int*)alloc((size_t)NE * CAP_E * 4);
  int* itemsV = (int*)alloc((size_t)NV * CAP_V * 4);
  uint32* pairE = (uint32*)alloc((size_t)NB_E * CAPB_E * 4);
  uint32* pairV = (uint32*)alloc((size_t)NB_V * CAPB_V * 4);
  uint2* ovfE  = (uint2*)alloc((size_t)OVF_CAP * 8);
  uint2* ovfV  = (uint2*)alloc((size_t)OVF_CAP * 8);
  int* curAll = (int*)alloc((size_t)(NB_E + NB_V + 2) * 4);
  int* curE = curAll;
  int* curV = curAll + NB_E;
  int* ovfCnt = curAll + NB_E + NB_V;

  int nzero = NB_E + NB_V + 2;
  zero_misc<<<(nzero + 255) / 256, 256, 0, stream>>>(curAll, nzero,
                                                     x_curh + (size_t)NV * 128,
                                                     Xeh + (size_t)NE * 128);
  scatter_binned<<<N_TILES, 256, 0, stream>>>(vertex, edges, curE, curV, ovfCnt,
                                              pairE, pairV, ovfE, ovfV);
  expand<<<NB_E, 256, 0, stream>>>(pairE, curE, CAPB_E, ovfE, ovfCnt,
                                   itemsE, CAP_E, cntE, NE, 16, NV);
  expand<<<NB_V, 256, 0, stream>>>(pairV, curV, CAPB_V, ovfV, ovfCnt + 1,
                                   itemsV, CAP_V, cntV, NV, 8, NE);
  prep_weights<<<(5 * 16384 + 255) / 256, 256, 0, stream>>>(W0, Ws, WT);

  int gblocks = (NV + 127) / 128;
  int fblocks = (NV + 63) / 64;
  gemm_first<<<gblocks, 256, 0, stream>>>(x, WT, b0, x_curh, x0h, NV);

  for (int i = 0; i < 4; i++) {
    edge_agg<<<NE / 16, 256, 0, stream>>>(x_curh, cntE, itemsE, Xeh);
    gemm_fused<<<fblocks, 256, 0, stream>>>(Xeh, cntV, itemsV, x0h,
                                            WT + (size_t)(1 + i) * 16384, x_curh, NV);
  }
  gemm_out<<<gblocks, 256, 0, stream>>>(x_curh, Wout, bout, out, NV);
}